// Round 5
// baseline (100.360 us; speedup 1.0000x reference)
//
#include <hip/hip_runtime.h>
#include <hip/hip_bf16.h>

#define N_CODECS 1024
#define EPS 1e-8f
#define HIST_BLOCKS 256        // 1 block/CU, 1024 thr = 16 waves/CU
#define CHUNKS 16              // stage-2: 16 blocks, each sums 16 partial rows

// native vector type accepted by __builtin_nontemporal_load
typedef int v4i __attribute__((ext_vector_type(4)));

// ws layout:
//   gpart : packed u16 [HIST_BLOCKS][N_CODECS] = 512 KB (as [256][512] uint)
//   p2    : u32 [CHUNKS][N_CODECS]             = 64 KB
//   done  : u32                                = 4 B

// ---------------------------------------------------------------------------
// Kernel 1: per-block LDS histogram -> packed u16 partial (plain stores only).
// 256 blocks x 1024 threads; each thread processes exactly 16 int4 (64 elems).
// Per-block-per-bin expected count = 64 (binomial, max ~150) -> u16 safe.
// Block 0 re-zeroes the done-counter for kernel 2 (safe: kernel boundary).
// ---------------------------------------------------------------------------
__global__ void __launch_bounds__(1024) hist_partial_kernel(
        const int* __restrict__ idx,
        unsigned int* __restrict__ gpart_u32,   // [HIST_BLOCKS][N_CODECS/2]
        unsigned int* __restrict__ done,
        int n4) {
    __shared__ unsigned int lcounts[N_CODECS];
    lcounts[threadIdx.x & (N_CODECS - 1)] = 0u;   // 1024 threads, 1024 bins
    if (blockIdx.x == 0 && threadIdx.x == 0) *done = 0u;
    __syncthreads();

    const v4i* __restrict__ idx4 = (const v4i*)idx;
    int stride = gridDim.x * 1024;
    for (int i = blockIdx.x * 1024 + threadIdx.x; i < n4; i += stride) {
        v4i v = __builtin_nontemporal_load(&idx4[i]);  // streamed, read-once
        atomicAdd(&lcounts[v.x], 1u);   // LDS atomics only
        atomicAdd(&lcounts[v.y], 1u);
        atomicAdd(&lcounts[v.z], 1u);
        atomicAdd(&lcounts[v.w], 1u);
    }
    __syncthreads();

    // pack two bins per uint: column c <- bins (2c, 2c+1); threads 0..511 store
    if (threadIdx.x < N_CODECS / 2) {
        unsigned int* __restrict__ mypart =
            gpart_u32 + (size_t)blockIdx.x * (N_CODECS / 2);
        mypart[threadIdx.x] =
            lcounts[2 * threadIdx.x] | (lcounts[2 * threadIdx.x + 1] << 16);
    }
}

// ---------------------------------------------------------------------------
// Kernel 2 (fused reduce + finalize): 16 blocks x 256 threads.
// Block c sums partial rows [c*16, c*16+16) into p2[c][*]; last block done
// (device-scope counter) computes entropy + perplexity.
// ---------------------------------------------------------------------------
__global__ void __launch_bounds__(256) reduce_finalize_kernel(
        const unsigned int* __restrict__ gpart_u32,  // [HIST_BLOCKS][512]
        unsigned int* __restrict__ p2,               // [CHUNKS][N_CODECS]
        unsigned int* __restrict__ done,
        float* __restrict__ out,
        float invN) {
    const int c = blockIdx.x;
    const int t = threadIdx.x;
    const int rows_per_chunk = HIST_BLOCKS / CHUNKS;   // 16
    const unsigned int* __restrict__ base =
        gpart_u32 + (size_t)(c * rows_per_chunk) * 512;

    unsigned int s0lo = 0, s0hi = 0, s1lo = 0, s1hi = 0;
    #pragma unroll
    for (int k = 0; k < rows_per_chunk; ++k) {
        unsigned int v0 = base[(size_t)k * 512 + t];
        unsigned int v1 = base[(size_t)k * 512 + 256 + t];
        s0lo += v0 & 0xFFFFu;  s0hi += v0 >> 16;
        s1lo += v1 & 0xFFFFu;  s1hi += v1 >> 16;
    }
    // col t -> bins (2t, 2t+1); col 256+t -> bins (512+2t, 512+2t+1)
    p2[c * N_CODECS + 2 * t]           = s0lo;
    p2[c * N_CODECS + 2 * t + 1]       = s0hi;
    p2[c * N_CODECS + 512 + 2 * t]     = s1lo;
    p2[c * N_CODECS + 512 + 2 * t + 1] = s1hi;

    __threadfence();       // release: make p2 stores device-visible
    __syncthreads();

    __shared__ bool amLast;
    if (t == 0) {
        unsigned int prev = atomicAdd(done, 1u);   // device-scope
        amLast = (prev == (unsigned int)(gridDim.x - 1));
    }
    __syncthreads();
    if (!amLast) return;

    __threadfence();       // acquire: see all other blocks' p2 stores

    float local = 0.0f;
    #pragma unroll
    for (int i = 0; i < N_CODECS / 256; ++i) {
        int b = i * 256 + t;
        unsigned int cnt = 0;
        #pragma unroll
        for (int ch = 0; ch < CHUNKS; ++ch) cnt += p2[ch * N_CODECS + b];
        float p = (float)cnt * invN;
        local += p * __logf(p + EPS);
    }

    #pragma unroll
    for (int off = 32; off > 0; off >>= 1) local += __shfl_down(local, off, 64);

    __shared__ float wsum[4];
    int wave = t >> 6, lane = t & 63;
    if (lane == 0) wsum[wave] = local;
    __syncthreads();
    if (t == 0) out[0] = __expf(-(wsum[0] + wsum[1] + wsum[2] + wsum[3]));
}

extern "C" void kernel_launch(void* const* d_in, const int* in_sizes, int n_in,
                              void* d_out, int out_size, void* d_ws, size_t ws_size,
                              hipStream_t stream) {
    const int* indices = (const int*)d_in[0];
    int n = in_sizes[0];             // 16 * 1048576 = 16,777,216
    float* out = (float*)d_out;

    unsigned int* gpart = (unsigned int*)d_ws;                          // 512 KB
    unsigned int* p2    = gpart + (size_t)HIST_BLOCKS * (N_CODECS / 2); // 64 KB
    unsigned int* done  = p2 + (size_t)CHUNKS * N_CODECS;               // 4 B

    int n4 = n >> 2;

    hist_partial_kernel<<<HIST_BLOCKS, 1024, 0, stream>>>(indices, gpart, done, n4);
    reduce_finalize_kernel<<<CHUNKS, 256, 0, stream>>>(gpart, p2, done, out,
                                                       1.0f / (float)n);
}

// Round 6
// 93.209 us; speedup vs baseline: 1.0767x; 1.0767x over previous
//
#include <hip/hip_runtime.h>
#include <hip/hip_bf16.h>

#define N_CODECS 1024
#define EPS 1e-8f
#define HIST_BLOCKS 1024
#define CHUNKS 16              // 1024 partials reduced in 16 chunks of 64

// ---------------------------------------------------------------------------
// Kernel 1: per-block LDS histogram -> private partial in d_ws (NO global
// atomics). Plain cached int4 loads (input is L3-resident after the harness's
// restore copy — do NOT use non-temporal loads, that bypasses L3: R5 showed
// +6us). Two independent loads per iteration for memory-level parallelism.
// ---------------------------------------------------------------------------
__global__ void __launch_bounds__(256) hist_partial_kernel(
        const int* __restrict__ idx,
        unsigned int* __restrict__ gpart,   // [HIST_BLOCKS][N_CODECS]
        int n4) {
    __shared__ unsigned int lcounts[N_CODECS];
    #pragma unroll
    for (int i = threadIdx.x; i < N_CODECS; i += 256) lcounts[i] = 0u;
    __syncthreads();

    const int4* __restrict__ idx4 = (const int4*)idx;
    const int stride = gridDim.x * 256;     // 262144
    for (int i = blockIdx.x * 256 + threadIdx.x; i < n4; i += 2 * stride) {
        int4 a = idx4[i];
        int j = i + stride;
        bool has_b = (j < n4);
        int4 b = has_b ? idx4[j] : make_int4(0, 0, 0, 0);

        atomicAdd(&lcounts[a.x], 1u);   // LDS atomics only
        atomicAdd(&lcounts[a.y], 1u);
        atomicAdd(&lcounts[a.z], 1u);
        atomicAdd(&lcounts[a.w], 1u);
        if (has_b) {
            atomicAdd(&lcounts[b.x], 1u);
            atomicAdd(&lcounts[b.y], 1u);
            atomicAdd(&lcounts[b.z], 1u);
            atomicAdd(&lcounts[b.w], 1u);
        }
    }
    __syncthreads();

    // contention-free merge: plain coalesced stores to this block's slice
    unsigned int* __restrict__ mypart = gpart + (size_t)blockIdx.x * N_CODECS;
    #pragma unroll
    for (int i = 0; i < N_CODECS / 256; ++i) {
        int b = i * 256 + threadIdx.x;
        mypart[b] = lcounts[b];
    }
}

// ---------------------------------------------------------------------------
// Kernel 2: reduce 1024 partials -> 16 chunk partials (column sums).
// Grid: 64 blocks x 256 threads. Block (c,q): chunk c=blk>>2, quarter q=blk&3.
// Thread handles bin = q*256 + tid, sums 64 partials. Fully coalesced.
// ---------------------------------------------------------------------------
__global__ void __launch_bounds__(256) reduce_kernel(
        const unsigned int* __restrict__ gpart,   // [HIST_BLOCKS][N_CODECS]
        unsigned int* __restrict__ p2) {          // [CHUNKS][N_CODECS]
    int c = blockIdx.x >> 2;
    int q = blockIdx.x & 3;
    int bin = q * 256 + threadIdx.x;

    const unsigned int* __restrict__ base = gpart + (size_t)(c * 64) * N_CODECS + bin;
    unsigned int s0 = 0, s1 = 0, s2 = 0, s3 = 0;
    #pragma unroll 4
    for (int k = 0; k < 64; k += 4) {
        s0 += base[(size_t)(k + 0) * N_CODECS];
        s1 += base[(size_t)(k + 1) * N_CODECS];
        s2 += base[(size_t)(k + 2) * N_CODECS];
        s3 += base[(size_t)(k + 3) * N_CODECS];
    }
    p2[c * N_CODECS + bin] = s0 + s1 + s2 + s3;
}

// ---------------------------------------------------------------------------
// Kernel 3: finalize. 1 block x 1024 threads: sum 16 chunk values per bin,
// p = count/N, term = p*log(p+eps), block reduce, out = exp(-sum).
// ---------------------------------------------------------------------------
__global__ void __launch_bounds__(1024) finalize_kernel(
        const unsigned int* __restrict__ p2,      // [CHUNKS][N_CODECS]
        float* __restrict__ out,
        float invN) {
    int t = threadIdx.x;
    unsigned int cnt = 0;
    #pragma unroll
    for (int c = 0; c < CHUNKS; ++c) cnt += p2[c * N_CODECS + t];

    float p = (float)cnt * invN;
    float term = p * logf(p + EPS);

    #pragma unroll
    for (int off = 32; off > 0; off >>= 1) term += __shfl_down(term, off, 64);

    __shared__ float wsum[16];
    int wave = t >> 6;
    int lane = t & 63;
    if (lane == 0) wsum[wave] = term;
    __syncthreads();

    if (wave == 0) {
        float s = (lane < 16) ? wsum[lane] : 0.0f;
        #pragma unroll
        for (int off = 8; off > 0; off >>= 1) s += __shfl_down(s, off, 64);
        if (lane == 0) out[0] = expf(-s);
    }
}

extern "C" void kernel_launch(void* const* d_in, const int* in_sizes, int n_in,
                              void* d_out, int out_size, void* d_ws, size_t ws_size,
                              hipStream_t stream) {
    const int* indices = (const int*)d_in[0];
    int n = in_sizes[0];             // 16 * 1048576 = 16,777,216
    float* out = (float*)d_out;

    unsigned int* gpart = (unsigned int*)d_ws;                       // 4 MB
    unsigned int* p2    = gpart + (size_t)HIST_BLOCKS * N_CODECS;    // 64 KB

    int n4 = n >> 2;

    hist_partial_kernel<<<HIST_BLOCKS, 256, 0, stream>>>(indices, gpart, n4);
    reduce_kernel<<<CHUNKS * 4, 256, 0, stream>>>(gpart, p2);
    finalize_kernel<<<1, 1024, 0, stream>>>(p2, out, 1.0f / (float)n);
}